// Round 1
// baseline (776.715 us; speedup 1.0000x reference)
//
#include <hip/hip_runtime.h>

#define B_SZ 256
#define F_SZ 4
#define M_SZ 256
#define D_SZ 8192
#define NITER 10

typedef signed char i8;
typedef signed char c16 __attribute__((ext_vector_type(16)));
typedef int v4i __attribute__((ext_vector_type(4)));

// ---- workspace layout (bytes) ----
#define OFF_CB    ((size_t)0)                        // i8  [F][M][D]        8 MB
#define OFF_CBT   ((size_t)8 << 20)                  // i8  [F][D][M]        8 MB
#define OFF_IN8   ((size_t)16 << 20)                 // i8  [B][D]           2 MB
#define OFF_ESTA  ((size_t)18 << 20)                 // i8  [B][F][D]        8 MB
#define OFF_ESTB  ((size_t)26 << 20)                 // i8  [B][F][D]        8 MB
#define OFF_SIMX  ((size_t)34 << 20)                 // i8  [B][F][768]      0.75 MB
#define OFF_PART  ((size_t)35 << 20)                 // i32 [8][B][F][M]     8 MB
#define OFF_P1    ((size_t)43 << 20)                 // i32 [4][2][B][F][M]  8 MB
#define OFF_S32   ((size_t)51 << 20)                 // i32 [F][D]           128 KB
#define OFF_PDIG  (OFF_S32 + (size_t)F_SZ * D_SZ * 4)   // i8 [4][F][D]      128 KB
#define OFF_CHG   (OFF_PDIG + (size_t)4 * F_SZ * D_SZ)  // int[16]

#define NBFM (B_SZ * F_SZ * M_SZ)   // 262144

// ---------------- converts / init ----------------

__global__ __launch_bounds__(256) void k_cvt_cb(const float* __restrict__ src,
                                                i8* __restrict__ cb, i8* __restrict__ cbt) {
  __shared__ i8 tile[32][33];
  const int bid = blockIdx.x;           // 8192 = 4f * 8mt * 256dt
  const int f = bid >> 11;
  const int rem = bid & 2047;
  const int m0 = (rem >> 8) << 5;
  const int d0 = (rem & 255) << 5;
  const int t = threadIdx.x;
  const int i = t >> 3, j = (t & 7) << 2;
  const float4 v = *(const float4*)(src + ((size_t)(f * M_SZ + m0 + i)) * D_SZ + d0 + j);
  char4 c;
  c.x = v.x > 0.f ? 1 : -1;
  c.y = v.y > 0.f ? 1 : -1;
  c.z = v.z > 0.f ? 1 : -1;
  c.w = v.w > 0.f ? 1 : -1;
  *(char4*)(cb + ((size_t)(f * M_SZ + m0 + i)) * D_SZ + d0 + j) = c;
  tile[i][j + 0] = c.x; tile[i][j + 1] = c.y; tile[i][j + 2] = c.z; tile[i][j + 3] = c.w;
  __syncthreads();
  const int dd = t >> 3, jm = (t & 7) << 2;
  char4 o;
  o.x = tile[jm + 0][dd]; o.y = tile[jm + 1][dd]; o.z = tile[jm + 2][dd]; o.w = tile[jm + 3][dd];
  *(char4*)(cbt + ((size_t)(f * D_SZ + d0 + dd)) * M_SZ + m0 + jm) = o;
}

__global__ __launch_bounds__(256) void k_cvt_in(const float* __restrict__ src, i8* __restrict__ dst) {
  const int idx = blockIdx.x * 256 + threadIdx.x;   // 524288 float4s
  const float4 v = ((const float4*)src)[idx];
  char4 c;
  c.x = v.x > 0.f ? 1 : -1;
  c.y = v.y > 0.f ? 1 : -1;
  c.z = v.z > 0.f ? 1 : -1;
  c.w = v.w > 0.f ? 1 : -1;
  ((char4*)dst)[idx] = c;
}

__global__ __launch_bounds__(256) void k_S(const i8* __restrict__ cb, int* __restrict__ S) {
  const int id = blockIdx.x * 256 + threadIdx.x;    // 32768 = [f][d]
  const int f = id >> 13, d = id & 8191;
  const i8* p = cb + (size_t)f * M_SZ * D_SZ + d;
  int s = 0;
  for (int m = 0; m < M_SZ; ++m) s += p[(size_t)m * D_SZ];
  S[id] = s;
}

__global__ __launch_bounds__(256) void k_P(const int* __restrict__ S, i8* __restrict__ pdig) {
  const int d = blockIdx.x * 256 + threadIdx.x;     // 8192
  const int s0 = S[d], s1 = S[D_SZ + d], s2 = S[2 * D_SZ + d], s3 = S[3 * D_SZ + d];
  int P[4];
  P[0] = s1 * s2 * s3;
  P[1] = s0 * s2 * s3;
  P[2] = s0 * s1 * s3;
  P[3] = s0 * s1 * s2;
  for (int f = 0; f < 4; ++f) {
    int x = P[f];
    #pragma unroll
    for (int p = 0; p < 3; ++p) {
      int r = (x + 64) >> 7;          // radix-128 signed digits in [-64,63]
      int dg = x - (r << 7);
      pdig[((size_t)(p * F_SZ + f)) * D_SZ + d] = (i8)dg;
      x = r;
    }
    pdig[((size_t)(3 * F_SZ + f)) * D_SZ + d] = (i8)x;
  }
}

// ---------------- stage A GEMM (sim) ----------------
// MODE 0: generic iter, A = input * prod(est others), split-K s=8 -> part[s]
// MODE 1: final sim, A = est itself, split-K s=8 -> part[s]
// MODE 2: iteration 1, A = input, B = digit_p(P)*cb, split-K s=2, planes p=4 -> p1[(p*2+s)]
template<int MODE>
__global__ __launch_bounds__(256) void ga_kernel(
    const i8* __restrict__ est, const i8* __restrict__ in8,
    const i8* __restrict__ cb, const i8* __restrict__ pdig,
    int* __restrict__ part)
{
  __shared__ __align__(16) i8 lA[64 * 48];
  __shared__ __align__(16) i8 lB[128 * 48];

  const int bid = blockIdx.x;   // always 256 blocks
  int s, p, f, ct;
  if (MODE == 2) { s = bid & 1; p = (bid >> 1) & 3; f = (bid >> 3) & 3; ct = bid >> 5; }
  else           { s = bid & 7; p = 0;              f = (bid >> 3) & 3; ct = bid >> 5; }
  const int b0 = (ct >> 1) * 64;
  const int m0 = (ct & 1) * 128;
  const int ksteps = (MODE == 2) ? 128 : 32;
  const int kbase  = (MODE == 2) ? (s << 12) : (s << 10);

  const int t = threadIdx.x;
  const int lane = t & 63;
  const int wv = t >> 6;
  const int wrow = (wv >> 1) * 32;
  const int wcol = (wv & 1) * 64;

  const int arow = t >> 1;             // B rows 0..127 ; A rows use t<128 (0..63)
  const int aoff = (t & 1) * 16;
  const i8* pB  = cb   + ((size_t)(f * M_SZ + m0 + arow)) * D_SZ + aoff;
  const i8* pDg = pdig + ((size_t)(p * F_SZ + f)) * D_SZ + aoff;
  const i8* pIn = in8  + (size_t)(b0 + arow) * D_SZ + aoff;
  const i8* pA0 = nullptr; const i8* pA1 = nullptr; const i8* pA2 = nullptr;
  if (MODE == 0) {
    int ffs[3]; int c = 0;
    for (int ff = 0; ff < 4; ++ff) if (ff != f) ffs[c++] = ff;
    pA0 = est + ((size_t)((b0 + arow) * F_SZ + ffs[0])) * D_SZ + aoff;
    pA1 = est + ((size_t)((b0 + arow) * F_SZ + ffs[1])) * D_SZ + aoff;
    pA2 = est + ((size_t)((b0 + arow) * F_SZ + ffs[2])) * D_SZ + aoff;
  } else if (MODE == 1) {
    pA0 = est + ((size_t)((b0 + arow) * F_SZ + f)) * D_SZ + aoff;
  }

  v4i acc[2][4];
  #pragma unroll
  for (int tr = 0; tr < 2; ++tr)
    #pragma unroll
    for (int tc = 0; tc < 4; ++tc) acc[tr][tc] = 0;

  c16 va = 0, vb = 0;
  {
    const int kk = kbase;
    vb = *(const c16*)(pB + kk);
    if (MODE == 2) vb = vb * (*(const c16*)(pDg + kk));
    if (t < 128) {
      if (MODE == 0)      va = (*(const c16*)(pIn + kk)) * (*(const c16*)(pA0 + kk))
                             * (*(const c16*)(pA1 + kk)) * (*(const c16*)(pA2 + kk));
      else if (MODE == 1) va = *(const c16*)(pA0 + kk);
      else                va = *(const c16*)(pIn + kk);
    }
  }

  for (int j = 0; j < ksteps; ++j) {
    c16 sa = va, sb = vb;
    if (j + 1 < ksteps) {
      const int kk = kbase + (j + 1) * 32;
      vb = *(const c16*)(pB + kk);
      if (MODE == 2) vb = vb * (*(const c16*)(pDg + kk));
      if (t < 128) {
        if (MODE == 0)      va = (*(const c16*)(pIn + kk)) * (*(const c16*)(pA0 + kk))
                               * (*(const c16*)(pA1 + kk)) * (*(const c16*)(pA2 + kk));
        else if (MODE == 1) va = *(const c16*)(pA0 + kk);
        else                va = *(const c16*)(pIn + kk);
      }
    }
    __syncthreads();
    if (t < 128) *(c16*)&lA[arow * 48 + aoff] = sa;
    *(c16*)&lB[arow * 48 + aoff] = sb;
    __syncthreads();

    const int rsel = lane & 15;
    const int kq = (lane >> 4) * 8;
    long af[2], bf[4];
    #pragma unroll
    for (int tr = 0; tr < 2; ++tr) af[tr] = *(const long*)&lA[(wrow + tr * 16 + rsel) * 48 + kq];
    #pragma unroll
    for (int tc = 0; tc < 4; ++tc) bf[tc] = *(const long*)&lB[(wcol + tc * 16 + rsel) * 48 + kq];
    #pragma unroll
    for (int tr = 0; tr < 2; ++tr)
      #pragma unroll
      for (int tc = 0; tc < 4; ++tc)
        acc[tr][tc] = __builtin_amdgcn_mfma_i32_16x16x32_i8(af[tr], bf[tc], acc[tr][tc], 0, 0, 0);
  }

  const int colb = lane & 15;
  const int rowq = (lane >> 4) * 4;
  const size_t obase = (MODE == 2) ? ((size_t)(p * 2 + s) * NBFM) : ((size_t)s * NBFM);
  #pragma unroll
  for (int tr = 0; tr < 2; ++tr)
    #pragma unroll
    for (int tc = 0; tc < 4; ++tc)
      #pragma unroll
      for (int r = 0; r < 4; ++r) {
        const int b = b0 + wrow + tr * 16 + rowq + r;
        const int m = m0 + wcol + tc * 16 + colb;
        part[obase + (((size_t)(b * F_SZ + f)) << 8) + m] = acc[tr][tc][r];
      }
}

// ---------------- digit conversion ----------------

__global__ __launch_bounds__(256) void k_digits(const int* __restrict__ part, i8* __restrict__ simx) {
  const int idx = blockIdx.x * 256 + threadIdx.x;   // [b*4+f]*256 + m
  int sim = 0;
  #pragma unroll
  for (int s = 0; s < 8; ++s) sim += part[(size_t)s * NBFM + idx];
  const int d1 = (sim + 128) >> 8;
  const int d0 = sim - (d1 << 8);
  const size_t bf = (size_t)(idx >> 8);
  const int m = idx & 255;
  simx[bf * 768 + m] = (i8)d0;
  simx[bf * 768 + 256 + m] = (i8)d1;
}

__global__ __launch_bounds__(256) void k_digits1(const int* __restrict__ p1, i8* __restrict__ simx) {
  const int idx = blockIdx.x * 256 + threadIdx.x;
  long long sim = 0;
  #pragma unroll
  for (int p = 3; p >= 0; --p) {
    long long g = (long long)p1[(size_t)(p * 2 + 0) * NBFM + idx]
                + (long long)p1[(size_t)(p * 2 + 1) * NBFM + idx];
    sim = sim * 128 + g;
  }
  int x = (int)sim;
  const int r1 = (x + 128) >> 8;
  const int d0 = x - (r1 << 8);
  const int r2 = (r1 + 128) >> 8;
  const int d1 = r1 - (r2 << 8);
  const size_t bf = (size_t)(idx >> 8);
  const int m = idx & 255;
  simx[bf * 768 + m] = (i8)d0;
  simx[bf * 768 + 256 + m] = (i8)d1;
  simx[bf * 768 + 512 + m] = (i8)r2;
}

// ---------------- stage B GEMM (out -> sign -> est) ----------------

template<int NP, bool FIRST>
__global__ __launch_bounds__(256) void gb_kernel(
    const i8* __restrict__ simx, const i8* __restrict__ cbt,
    const i8* __restrict__ est_prev, const int* __restrict__ S32,
    i8* __restrict__ est_next, int* __restrict__ changed, int it)
{
  __shared__ __align__(16) i8 lA[64 * 48];
  __shared__ __align__(16) i8 lB[128 * 48];
  __shared__ int chgf;

  const int bid = blockIdx.x;   // 1024 blocks
  const int f = bid & 3;
  const int ct = bid >> 2;
  const int b0 = (ct >> 6) * 64;
  const int d0 = (ct & 63) * 128;

  const int t = threadIdx.x;
  if (t == 0) chgf = 0;
  const int lane = t & 63;
  const int wv = t >> 6;
  const int wrow = (wv >> 1) * 32;
  const int wcol = (wv & 1) * 64;

  const int arow = t >> 1;
  const int aoff = (t & 1) * 16;
  const i8* pA = simx + ((size_t)((b0 + arow) * F_SZ + f)) * 768 + aoff;  // + p*256 + j*32
  const i8* pB = cbt + ((size_t)(f * D_SZ + d0 + arow)) * M_SZ + aoff;    // + j*32

  v4i acc[NP][2][4];
  #pragma unroll
  for (int pp = 0; pp < NP; ++pp)
    #pragma unroll
    for (int tr = 0; tr < 2; ++tr)
      #pragma unroll
      for (int tc = 0; tc < 4; ++tc) acc[pp][tr][tc] = 0;

  #pragma unroll
  for (int pp = 0; pp < NP; ++pp) {
    c16 va = 0, vb = 0;
    if (t < 128) va = *(const c16*)(pA + pp * 256);
    vb = *(const c16*)(pB);
    for (int j = 0; j < 8; ++j) {
      c16 sa = va, sb = vb;
      if (j < 7) {
        if (t < 128) va = *(const c16*)(pA + pp * 256 + (j + 1) * 32);
        vb = *(const c16*)(pB + (j + 1) * 32);
      }
      __syncthreads();
      if (t < 128) *(c16*)&lA[arow * 48 + aoff] = sa;
      *(c16*)&lB[arow * 48 + aoff] = sb;
      __syncthreads();

      const int rsel = lane & 15;
      const int kq = (lane >> 4) * 8;
      long af[2], bf[4];
      #pragma unroll
      for (int tr = 0; tr < 2; ++tr) af[tr] = *(const long*)&lA[(wrow + tr * 16 + rsel) * 48 + kq];
      #pragma unroll
      for (int tc = 0; tc < 4; ++tc) bf[tc] = *(const long*)&lB[(wcol + tc * 16 + rsel) * 48 + kq];
      #pragma unroll
      for (int tr = 0; tr < 2; ++tr)
        #pragma unroll
        for (int tc = 0; tc < 4; ++tc)
          acc[pp][tr][tc] = __builtin_amdgcn_mfma_i32_16x16x32_i8(af[tr], bf[tc], acc[pp][tr][tc], 0, 0, 0);
    }
  }

  bool ch = false;
  const int colb = lane & 15;
  const int rowq = (lane >> 4) * 4;
  #pragma unroll
  for (int tr = 0; tr < 2; ++tr)
    #pragma unroll
    for (int tc = 0; tc < 4; ++tc)
      #pragma unroll
      for (int r = 0; r < 4; ++r) {
        long long o = (long long)acc[0][tr][tc][r];
        if (NP > 1) o += 256LL * (long long)acc[1][tr][tc][r];
        if (NP > 2) o += 65536LL * (long long)acc[2][tr][tc][r];
        const i8 sg = (i8)((o > 0) - (o < 0));
        const int b = b0 + wrow + tr * 16 + rowq + r;
        const int d = d0 + wcol + tc * 16 + colb;
        const size_t ad = ((size_t)(b * F_SZ + f)) * D_SZ + d;
        if (FIRST) ch |= ((int)sg != S32[f * D_SZ + d]);
        else       ch |= (sg != est_prev[ad]);
        est_next[ad] = sg;
      }
  if (ch) chgf = 1;
  __syncthreads();
  if (t == 0 && chgf) atomicOr(&changed[it], 1);
}

// ---------------- argmax + k ----------------

__global__ __launch_bounds__(256) void k_argmax(const int* __restrict__ part,
                                                const int* __restrict__ chg,
                                                int* __restrict__ out) {
  __shared__ long long red[256];
  const int bf = blockIdx.x;       // 1024 = b*4+f
  const int m = threadIdx.x;
  int sim = 0;
  #pragma unroll
  for (int s = 0; s < 8; ++s) sim += part[(size_t)s * NBFM + bf * 256 + m];
  red[m] = ((long long)sim << 32) | (long long)(unsigned)(255 - m);
  __syncthreads();
  for (int s = 128; s > 0; s >>= 1) {
    if (m < s) { if (red[m + s] > red[m]) red[m] = red[m + s]; }
    __syncthreads();
  }
  if (m == 0) {
    out[bf] = 255 - (int)(red[0] & 0xFFFF);
    if (bf == 0) {
      int k = NITER;
      for (int i = 1; i <= NITER; ++i) if (chg[i] == 0) { k = i; break; }
      out[B_SZ * F_SZ] = k;
    }
  }
}

// ---------------- host ----------------

extern "C" void kernel_launch(void* const* d_in, const int* in_sizes, int n_in,
                              void* d_out, int out_size, void* d_ws, size_t ws_size,
                              hipStream_t stream) {
  const float* f_in = (const float*)d_in[0];   // [B][D]
  const float* f_cb = (const float*)d_in[1];   // [F][M][D]
  int* out = (int*)d_out;
  char* ws = (char*)d_ws;

  i8*  cb8  = (i8*)(ws + OFF_CB);
  i8*  cbt8 = (i8*)(ws + OFF_CBT);
  i8*  in8  = (i8*)(ws + OFF_IN8);
  i8*  estA = (i8*)(ws + OFF_ESTA);
  i8*  estB = (i8*)(ws + OFF_ESTB);
  i8*  simx = (i8*)(ws + OFF_SIMX);
  int* part = (int*)(ws + OFF_PART);
  int* p1   = (int*)(ws + OFF_P1);
  int* S32  = (int*)(ws + OFF_S32);
  i8*  pdig = (i8*)(ws + OFF_PDIG);
  int* chg  = (int*)(ws + OFF_CHG);

  hipMemsetAsync(chg, 0, 64, stream);
  k_cvt_cb<<<dim3(8192), dim3(256), 0, stream>>>(f_cb, cb8, cbt8);
  k_cvt_in<<<dim3(2048), dim3(256), 0, stream>>>(f_in, in8);
  k_S<<<dim3(128), dim3(256), 0, stream>>>(cb8, S32);
  k_P<<<dim3(32), dim3(256), 0, stream>>>(S32, pdig);

  // iteration 1 (big-integer est0 handled via P digit planes)
  ga_kernel<2><<<dim3(256), dim3(256), 0, stream>>>(nullptr, in8, cb8, pdig, p1);
  k_digits1<<<dim3(1024), dim3(256), 0, stream>>>(p1, simx);
  gb_kernel<3, true><<<dim3(1024), dim3(256), 0, stream>>>(simx, cbt8, nullptr, S32, estA, chg, 1);

  i8* cur = estA; i8* nxt = estB;
  for (int it = 2; it <= NITER; ++it) {
    ga_kernel<0><<<dim3(256), dim3(256), 0, stream>>>(cur, in8, cb8, nullptr, part);
    k_digits<<<dim3(1024), dim3(256), 0, stream>>>(part, simx);
    gb_kernel<2, false><<<dim3(1024), dim3(256), 0, stream>>>(simx, cbt8, cur, nullptr, nxt, chg, it);
    i8* tmp = cur; cur = nxt; nxt = tmp;
  }

  // final sim + argmax + k
  ga_kernel<1><<<dim3(256), dim3(256), 0, stream>>>(cur, in8, cb8, nullptr, part);
  k_argmax<<<dim3(1024), dim3(256), 0, stream>>>(part, chg, out);
}

// Round 2
// 592.056 us; speedup vs baseline: 1.3119x; 1.3119x over previous
//
#include <hip/hip_runtime.h>

#define B_SZ 256
#define F_SZ 4
#define M_SZ 256
#define D_SZ 8192
#define NITER 10

typedef signed char i8;
typedef unsigned long long u64;
typedef signed char c16 __attribute__((ext_vector_type(16)));
typedef int v4i __attribute__((ext_vector_type(4)));

#define NBFM (B_SZ * F_SZ * M_SZ)   // 262144

// ---- workspace layout (bytes) ----
#define OFF_CB    ((size_t)0)          // i8  [F][M][D]      8 MB
#define OFF_CBT   ((size_t)8  << 20)   // i8  [F][D][M]      8 MB
#define OFF_IN8   ((size_t)16 << 20)   // i8  [B][D]         2 MB
#define OFF_CBBT  ((size_t)18 << 20)   // u64 [F][128][M]    1 MB
#define OFF_INB   ((size_t)19 << 20)   // u64 [B][128]       256 KB
#define OFF_ESB0  ((size_t)20 << 20)   // u64 [B][F][128]    1 MB  (sign bits)
#define OFF_EZB0  ((size_t)21 << 20)   // u64 [B][F][128]    1 MB  (zero bits)
#define OFF_ESB1  ((size_t)22 << 20)
#define OFF_EZB1  ((size_t)23 << 20)
#define OFF_SIMX  ((size_t)24 << 20)   // i8  [B*F][768]     768 KB (digit planes)
#define OFF_SIMI  ((size_t)25 << 20)   // i32 [B*F][256]     1 MB   (final sim)
#define OFF_P1    ((size_t)26 << 20)   // i32 [16][B*F*M]    16 MB  (iter1 partials)
#define OFF_S32   ((size_t)42 << 20)   // i32 [F][D]         128 KB
#define OFF_PDIG  (OFF_S32 + (size_t)F_SZ * D_SZ * 4)   // i8 [4][F][D] 128 KB
#define OFF_CHG   (OFF_PDIG + (size_t)4 * F_SZ * D_SZ)  // int[16]

// ---------------- converts / init ----------------

__global__ __launch_bounds__(256) void k_cvt_cb(const float* __restrict__ src,
                                                i8* __restrict__ cb, i8* __restrict__ cbt) {
  __shared__ i8 tile[32][33];
  const int bid = blockIdx.x;           // 8192 = 4f * 8mt * 256dt
  const int f = bid >> 11;
  const int rem = bid & 2047;
  const int m0 = (rem >> 8) << 5;
  const int d0 = (rem & 255) << 5;
  const int t = threadIdx.x;
  const int i = t >> 3, j = (t & 7) << 2;
  const float4 v = *(const float4*)(src + ((size_t)(f * M_SZ + m0 + i)) * D_SZ + d0 + j);
  char4 c;
  c.x = v.x > 0.f ? 1 : -1;
  c.y = v.y > 0.f ? 1 : -1;
  c.z = v.z > 0.f ? 1 : -1;
  c.w = v.w > 0.f ? 1 : -1;
  *(char4*)(cb + ((size_t)(f * M_SZ + m0 + i)) * D_SZ + d0 + j) = c;
  tile[i][j + 0] = c.x; tile[i][j + 1] = c.y; tile[i][j + 2] = c.z; tile[i][j + 3] = c.w;
  __syncthreads();
  const int dd = t >> 3, jm = (t & 7) << 2;
  char4 o;
  o.x = tile[jm + 0][dd]; o.y = tile[jm + 1][dd]; o.z = tile[jm + 2][dd]; o.w = tile[jm + 3][dd];
  *(char4*)(cbt + ((size_t)(f * D_SZ + d0 + dd)) * M_SZ + m0 + jm) = o;
}

__global__ __launch_bounds__(256) void k_cvt_in(const float* __restrict__ src, i8* __restrict__ dst) {
  const int idx = blockIdx.x * 256 + threadIdx.x;   // 524288 float4s
  const float4 v = ((const float4*)src)[idx];
  char4 c;
  c.x = v.x > 0.f ? 1 : -1;
  c.y = v.y > 0.f ? 1 : -1;
  c.z = v.z > 0.f ? 1 : -1;
  c.w = v.w > 0.f ? 1 : -1;
  ((char4*)dst)[idx] = c;
}

__global__ __launch_bounds__(256) void k_pack_cb(const i8* __restrict__ cb, u64* __restrict__ cbbT) {
  const int id = blockIdx.x * 256 + threadIdx.x;   // 131072 = f*32768 + w*256 + m
  const int f = id >> 15;
  const int rem = id & 32767;
  const int w = rem >> 8;
  const int m = rem & 255;
  const i8* src = cb + ((size_t)(f * M_SZ + m)) * D_SZ + w * 64;
  u64 r = 0;
  #pragma unroll
  for (int k = 0; k < 4; ++k) {
    c16 v = *(const c16*)(src + k * 16);
    u64 part = 0;
    #pragma unroll
    for (int j = 0; j < 16; ++j) part |= ((u64)(((unsigned char)v[j]) >> 7)) << j;
    r |= part << (k * 16);
  }
  cbbT[((size_t)(f * 128 + w)) * 256 + m] = r;
}

__global__ __launch_bounds__(256) void k_pack_in(const i8* __restrict__ in8, u64* __restrict__ inb) {
  const int id = blockIdx.x * 256 + threadIdx.x;   // 32768 = b*128 + w
  const int b = id >> 7;
  const int w = id & 127;
  const i8* src = in8 + (size_t)b * D_SZ + w * 64;
  u64 r = 0;
  #pragma unroll
  for (int k = 0; k < 4; ++k) {
    c16 v = *(const c16*)(src + k * 16);
    u64 part = 0;
    #pragma unroll
    for (int j = 0; j < 16; ++j) part |= ((u64)(((unsigned char)v[j]) >> 7)) << j;
    r |= part << (k * 16);
  }
  inb[(size_t)b * 128 + w] = r;
}

__global__ __launch_bounds__(256) void k_S(const i8* __restrict__ cb, int* __restrict__ S) {
  const int id = blockIdx.x * 256 + threadIdx.x;    // 32768 = [f][d]
  const int f = id >> 13, d = id & 8191;
  const i8* p = cb + (size_t)f * M_SZ * D_SZ + d;
  int s = 0;
  for (int m = 0; m < M_SZ; ++m) s += p[(size_t)m * D_SZ];
  S[id] = s;
}

__global__ __launch_bounds__(256) void k_P(const int* __restrict__ S, i8* __restrict__ pdig) {
  const int d = blockIdx.x * 256 + threadIdx.x;     // 8192
  const int s0 = S[d], s1 = S[D_SZ + d], s2 = S[2 * D_SZ + d], s3 = S[3 * D_SZ + d];
  int P[4];
  P[0] = s1 * s2 * s3;
  P[1] = s0 * s2 * s3;
  P[2] = s0 * s1 * s3;
  P[3] = s0 * s1 * s2;
  for (int f = 0; f < 4; ++f) {
    int x = P[f];
    #pragma unroll
    for (int p = 0; p < 3; ++p) {
      int r = (x + 64) >> 7;          // radix-128 signed digits in [-64,63]
      int dg = x - (r << 7);
      pdig[((size_t)(p * F_SZ + f)) * D_SZ + d] = (i8)dg;
      x = r;
    }
    pdig[((size_t)(3 * F_SZ + f)) * D_SZ + d] = (i8)x;
  }
}

// ---------------- iteration-1 stage A (MFMA, digit planes of P) ----------------
// grid 512: s(4 splits) x p(4 planes) x f(4) x ct(8)

__global__ __launch_bounds__(256) void ga2_kernel(
    const i8* __restrict__ in8, const i8* __restrict__ cb,
    const i8* __restrict__ pdig, int* __restrict__ p1)
{
  __shared__ __align__(16) i8 lA[64 * 48];
  __shared__ __align__(16) i8 lB[128 * 48];

  const int bid = blockIdx.x;
  const int s = bid & 3;
  const int p = (bid >> 2) & 3;
  const int f = (bid >> 4) & 3;
  const int ct = bid >> 6;
  const int b0 = (ct >> 1) * 64;
  const int m0 = (ct & 1) * 128;
  const int ksteps = 64;
  const int kbase = s << 11;

  const int t = threadIdx.x;
  const int lane = t & 63;
  const int wv = t >> 6;
  const int wrow = (wv >> 1) * 32;
  const int wcol = (wv & 1) * 64;

  const int arow = t >> 1;
  const int aoff = (t & 1) * 16;
  const i8* pB  = cb   + ((size_t)(f * M_SZ + m0 + arow)) * D_SZ + aoff;
  const i8* pDg = pdig + ((size_t)(p * F_SZ + f)) * D_SZ + aoff;
  const i8* pIn = in8  + (size_t)(b0 + arow) * D_SZ + aoff;

  v4i acc[2][4];
  #pragma unroll
  for (int tr = 0; tr < 2; ++tr)
    #pragma unroll
    for (int tc = 0; tc < 4; ++tc) acc[tr][tc] = 0;

  c16 va = 0, vb = 0;
  {
    const int kk = kbase;
    vb = (*(const c16*)(pB + kk)) * (*(const c16*)(pDg + kk));
    if (t < 128) va = *(const c16*)(pIn + kk);
  }

  for (int j = 0; j < ksteps; ++j) {
    c16 sa = va, sb = vb;
    if (j + 1 < ksteps) {
      const int kk = kbase + (j + 1) * 32;
      vb = (*(const c16*)(pB + kk)) * (*(const c16*)(pDg + kk));
      if (t < 128) va = *(const c16*)(pIn + kk);
    }
    __syncthreads();
    if (t < 128) *(c16*)&lA[arow * 48 + aoff] = sa;
    *(c16*)&lB[arow * 48 + aoff] = sb;
    __syncthreads();

    const int rsel = lane & 15;
    const int kq = (lane >> 4) * 8;
    long af[2], bf[4];
    #pragma unroll
    for (int tr = 0; tr < 2; ++tr) af[tr] = *(const long*)&lA[(wrow + tr * 16 + rsel) * 48 + kq];
    #pragma unroll
    for (int tc = 0; tc < 4; ++tc) bf[tc] = *(const long*)&lB[(wcol + tc * 16 + rsel) * 48 + kq];
    #pragma unroll
    for (int tr = 0; tr < 2; ++tr)
      #pragma unroll
      for (int tc = 0; tc < 4; ++tc)
        acc[tr][tc] = __builtin_amdgcn_mfma_i32_16x16x32_i8(af[tr], bf[tc], acc[tr][tc], 0, 0, 0);
  }

  const int colb = lane & 15;
  const int rowq = (lane >> 4) * 4;
  const size_t obase = (size_t)(p * 4 + s) * NBFM;
  #pragma unroll
  for (int tr = 0; tr < 2; ++tr)
    #pragma unroll
    for (int tc = 0; tc < 4; ++tc)
      #pragma unroll
      for (int r = 0; r < 4; ++r) {
        const int b = b0 + wrow + tr * 16 + rowq + r;
        const int m = m0 + wcol + tc * 16 + colb;
        p1[obase + (((size_t)(b * F_SZ + f)) << 8) + m] = acc[tr][tc][r];
      }
}

__global__ __launch_bounds__(256) void k_digits1(const int* __restrict__ p1, i8* __restrict__ simx) {
  const int idx = blockIdx.x * 256 + threadIdx.x;
  long long sim = 0;
  #pragma unroll
  for (int p = 3; p >= 0; --p) {
    long long g = 0;
    #pragma unroll
    for (int s = 0; s < 4; ++s) g += (long long)p1[(size_t)(p * 4 + s) * NBFM + idx];
    sim = sim * 128 + g;
  }
  int x = (int)sim;
  const int r1 = (x + 128) >> 8;
  const int d0 = x - (r1 << 8);
  const int r2 = (r1 + 128) >> 8;
  const int d1 = r1 - (r2 << 8);
  const size_t bf = (size_t)(idx >> 8);
  const int m = idx & 255;
  simx[bf * 768 + m] = (i8)d0;
  simx[bf * 768 + 256 + m] = (i8)d1;
  simx[bf * 768 + 512 + m] = (i8)r2;
}

// ---------------- bitwise stage A (iters >= 2 and final) ----------------
// MODE 0: A = in ^ es(f0)^es(f1)^es(f2), nz = ~(ez|ez|ez) -> simx 2 digit planes
// MODE 1: A = es[f], nz = ~ez[f]                          -> sim_int
// grid 512 = f(4) x btile(128, 2 rows each); 256 threads = 256 m

template<int MODE>
__global__ __launch_bounds__(256) void ga_bit(
    const u64* __restrict__ esb, const u64* __restrict__ ezb,
    const u64* __restrict__ inb, const u64* __restrict__ cbbT,
    i8* __restrict__ simx, int* __restrict__ sim_int)
{
  __shared__ u64 AL[128][4];    // [w][{s0,nz0,s1,nz1}]
  __shared__ int C0[2];

  const int bid = blockIdx.x;
  const int f = bid & 3;
  const int b0 = (bid >> 2) * 2;
  const int t = threadIdx.x;
  if (t < 2) C0[t] = 0;
  __syncthreads();

  {
    const int r = t >> 7, w = t & 127;
    const int b = b0 + r;
    u64 s, nz;
    if (MODE == 0) {
      int ffs[3]; int c = 0;
      for (int ff = 0; ff < 4; ++ff) if (ff != f) ffs[c++] = ff;
      const size_t base = (size_t)b * 4 * 128;
      s = inb[(size_t)b * 128 + w]
        ^ esb[base + ffs[0] * 128 + w] ^ esb[base + ffs[1] * 128 + w] ^ esb[base + ffs[2] * 128 + w];
      nz = ~(ezb[base + ffs[0] * 128 + w] | ezb[base + ffs[1] * 128 + w] | ezb[base + ffs[2] * 128 + w]);
    } else {
      const size_t a = ((size_t)b * 4 + f) * 128 + w;
      s = esb[a];
      nz = ~ezb[a];
    }
    AL[w][r * 2] = s;
    AL[w][r * 2 + 1] = nz;
    atomicAdd(&C0[r], __popcll(nz));
  }
  __syncthreads();

  const int m = t;
  int a0 = 0, a1 = 0;
  const u64* pc = cbbT + (size_t)f * 128 * 256 + m;
  for (int w = 0; w < 128; ++w) {
    const u64 cbw = pc[w * 256];
    const u64 s0 = AL[w][0], z0 = AL[w][1], s1 = AL[w][2], z1 = AL[w][3];
    a0 += (int)__popcll((s0 ^ cbw) & z0);
    a1 += (int)__popcll((s1 ^ cbw) & z1);
  }
  const int sim0 = C0[0] - 2 * a0;
  const int sim1 = C0[1] - 2 * a1;

  if (MODE == 0) {
    int d1 = (sim0 + 128) >> 8; int d0v = sim0 - (d1 << 8);
    const size_t bf0 = ((size_t)b0 * 4 + f) * 768;
    simx[bf0 + m] = (i8)d0v; simx[bf0 + 256 + m] = (i8)d1;
    d1 = (sim1 + 128) >> 8; d0v = sim1 - (d1 << 8);
    const size_t bf1 = ((size_t)(b0 + 1) * 4 + f) * 768;
    simx[bf1 + m] = (i8)d0v; simx[bf1 + 256 + m] = (i8)d1;
  } else {
    sim_int[((size_t)b0 * 4 + f) * 256 + m] = sim0;
    sim_int[((size_t)(b0 + 1) * 4 + f) * 256 + m] = sim1;
  }
}

// ---------------- stage B GEMM (out -> sign -> packed est bits) ----------------
// grid 1024 = f(4) x ct(256: 4 btiles x 64 dtiles). B staged once in frag-linear LDS.

template<int NP, bool FIRST>
__global__ __launch_bounds__(256) void gb_kernel(
    const i8* __restrict__ simx, const i8* __restrict__ cbt,
    const u64* __restrict__ esp, const u64* __restrict__ ezp,
    const int* __restrict__ S32,
    u64* __restrict__ esn, u64* __restrict__ ezn,
    int* __restrict__ changed, int it)
{
  __shared__ __align__(16) i8 lB[8 * 8 * 64 * 8];   // 32 KB: [ks][tile][lane][8]
  __shared__ int chgf;

  const int bid = blockIdx.x;
  const int f = bid & 3;
  const int ct = bid >> 2;
  const int b0 = (ct >> 6) * 64;
  const int d0 = (ct & 63) * 128;

  const int t = threadIdx.x;
  if (t == 0) chgf = 0;
  const int lane = t & 63;
  const int wv = t >> 6;
  const int wrow = (wv >> 1) * 32;
  const int wcol = (wv & 1) * 64;

  // ---- stage B tile into frag-linear LDS ----
  {
    const int c = t & 15;          // 16-byte chunk of m
    const int dr0 = t >> 4;        // base d row
    const int ks = c >> 1;
    const int q0 = (c & 1) * 2;
    #pragma unroll
    for (int i = 0; i < 8; ++i) {
      const int dr = dr0 + i * 16;
      union { c16 v; u64 u[2]; } x;
      x.v = *(const c16*)(cbt + ((size_t)(f * D_SZ + d0 + dr)) * M_SZ + c * 16);
      const int tile = dr >> 4;
      const int col = dr & 15;
      *(u64*)&lB[((((ks * 8 + tile) * 4 + q0) * 16 + col)) * 8] = x.u[0];
      *(u64*)&lB[((((ks * 8 + tile) * 4 + q0 + 1) * 16 + col)) * 8] = x.u[1];
    }
  }
  __syncthreads();

  v4i acc[NP][2][4];
  #pragma unroll
  for (int pp = 0; pp < NP; ++pp)
    #pragma unroll
    for (int tr = 0; tr < 2; ++tr)
      #pragma unroll
      for (int tc = 0; tc < 4; ++tc) acc[pp][tr][tc] = 0;

  const int rsel = lane & 15;
  const int kq = (lane >> 4) * 8;
  const int tb = wcol >> 4;

  #pragma unroll
  for (int ks = 0; ks < 8; ++ks) {
    long bf[4];
    #pragma unroll
    for (int tc = 0; tc < 4; ++tc)
      bf[tc] = *(const long*)&lB[((ks * 8 + tb + tc) * 64 + lane) * 8];
    #pragma unroll
    for (int pp = 0; pp < NP; ++pp) {
      long af[2];
      #pragma unroll
      for (int tr = 0; tr < 2; ++tr) {
        const int row = b0 + wrow + tr * 16 + rsel;
        af[tr] = *(const long*)(simx + ((size_t)(row * 4 + f)) * 768 + pp * 256 + ks * 32 + kq);
      }
      #pragma unroll
      for (int tr = 0; tr < 2; ++tr)
        #pragma unroll
        for (int tc = 0; tc < 4; ++tc)
          acc[pp][tr][tc] = __builtin_amdgcn_mfma_i32_16x16x32_i8(af[tr], bf[tc], acc[pp][tr][tc], 0, 0, 0);
    }
  }

  // ---- epilogue: sign, ballot-pack, change-detect, store ----
  bool chl = false;
  const int colb = lane & 15;

  #pragma unroll
  for (int tr = 0; tr < 2; ++tr) {
    unsigned long long bs[4][4], bz[4][4];   // [r][tc]
    #pragma unroll
    for (int r = 0; r < 4; ++r)
      #pragma unroll
      for (int tc = 0; tc < 4; ++tc) {
        int o = acc[0][tr][tc][r];
        if (NP > 1) o += acc[1][tr][tc][r] * 256;
        if (NP > 2) o += acc[2][tr][tc][r] * 65536;
        bs[r][tc] = __ballot(o < 0);
        bz[r][tc] = __ballot(o == 0);
        if (FIRST) {
          const int sg = (o > 0) - (o < 0);
          const int d = d0 + wcol + tc * 16 + colb;
          chl |= (sg != S32[f * D_SZ + d]);
        }
      }
    u64 ws = 0, wz = 0;
    #pragma unroll
    for (int rl = 0; rl < 16; ++rl) {
      const int g = rl >> 2, r = rl & 3;
      u64 vs = 0, vz = 0;
      #pragma unroll
      for (int tc = 0; tc < 4; ++tc) {
        vs |= ((bs[r][tc] >> (g * 16)) & 0xFFFFull) << (tc * 16);
        vz |= ((bz[r][tc] >> (g * 16)) & 0xFFFFull) << (tc * 16);
      }
      if (lane == rl) { ws = vs; wz = vz; }
    }
    if (lane < 16) {
      const int row = b0 + wrow + tr * 16 + lane;
      const size_t wi = ((size_t)(row * 4 + f)) * 128 + ((d0 + wcol) >> 6);
      if (!FIRST) chl |= (ws != esp[wi]) | (wz != ezp[wi]);
      esn[wi] = ws;
      ezn[wi] = wz;
    }
  }
  if (chl) atomicOr(&chgf, 1);
  __syncthreads();
  if (t == 0 && chgf) atomicOr(&changed[it], 1);
}

// ---------------- argmax + k ----------------

__global__ __launch_bounds__(256) void k_argmax(const int* __restrict__ sim_int,
                                                const int* __restrict__ chg,
                                                int* __restrict__ out) {
  __shared__ long long red[256];
  const int bf = blockIdx.x;       // 1024 = b*4+f
  const int m = threadIdx.x;
  const int sim = sim_int[(size_t)bf * 256 + m];
  red[m] = ((long long)sim << 32) | (long long)(unsigned)(255 - m);
  __syncthreads();
  for (int s = 128; s > 0; s >>= 1) {
    if (m < s) { if (red[m + s] > red[m]) red[m] = red[m + s]; }
    __syncthreads();
  }
  if (m == 0) {
    out[bf] = 255 - (int)(red[0] & 0xFFFF);
    if (bf == 0) {
      int k = NITER;
      for (int i = 1; i <= NITER; ++i) if (chg[i] == 0) { k = i; break; }
      out[B_SZ * F_SZ] = k;
    }
  }
}

// ---------------- host ----------------

extern "C" void kernel_launch(void* const* d_in, const int* in_sizes, int n_in,
                              void* d_out, int out_size, void* d_ws, size_t ws_size,
                              hipStream_t stream) {
  const float* f_in = (const float*)d_in[0];   // [B][D]
  const float* f_cb = (const float*)d_in[1];   // [F][M][D]
  int* out = (int*)d_out;
  char* ws = (char*)d_ws;

  i8*  cb8  = (i8*)(ws + OFF_CB);
  i8*  cbt8 = (i8*)(ws + OFF_CBT);
  i8*  in8  = (i8*)(ws + OFF_IN8);
  u64* cbbT = (u64*)(ws + OFF_CBBT);
  u64* inb  = (u64*)(ws + OFF_INB);
  u64* esb0 = (u64*)(ws + OFF_ESB0);
  u64* ezb0 = (u64*)(ws + OFF_EZB0);
  u64* esb1 = (u64*)(ws + OFF_ESB1);
  u64* ezb1 = (u64*)(ws + OFF_EZB1);
  i8*  simx = (i8*)(ws + OFF_SIMX);
  int* simI = (int*)(ws + OFF_SIMI);
  int* p1   = (int*)(ws + OFF_P1);
  int* S32  = (int*)(ws + OFF_S32);
  i8*  pdig = (i8*)(ws + OFF_PDIG);
  int* chg  = (int*)(ws + OFF_CHG);

  hipMemsetAsync(chg, 0, 64, stream);
  k_cvt_cb<<<dim3(8192), dim3(256), 0, stream>>>(f_cb, cb8, cbt8);
  k_cvt_in<<<dim3(2048), dim3(256), 0, stream>>>(f_in, in8);
  k_pack_cb<<<dim3(512), dim3(256), 0, stream>>>(cb8, cbbT);
  k_pack_in<<<dim3(128), dim3(256), 0, stream>>>(in8, inb);
  k_S<<<dim3(128), dim3(256), 0, stream>>>(cb8, S32);
  k_P<<<dim3(32), dim3(256), 0, stream>>>(S32, pdig);

  // iteration 1 (big-integer est0 via P digit planes, MFMA)
  ga2_kernel<<<dim3(512), dim3(256), 0, stream>>>(in8, cb8, pdig, p1);
  k_digits1<<<dim3(1024), dim3(256), 0, stream>>>(p1, simx);
  gb_kernel<3, true><<<dim3(1024), dim3(256), 0, stream>>>(
      simx, cbt8, nullptr, nullptr, S32, esb0, ezb0, chg, 1);

  u64* cs = esb0; u64* cz = ezb0; u64* ns = esb1; u64* nz = ezb1;
  for (int it = 2; it <= NITER; ++it) {
    ga_bit<0><<<dim3(512), dim3(256), 0, stream>>>(cs, cz, inb, cbbT, simx, nullptr);
    gb_kernel<2, false><<<dim3(1024), dim3(256), 0, stream>>>(
        simx, cbt8, cs, cz, nullptr, ns, nz, chg, it);
    u64* ts = cs; cs = ns; ns = ts;
    u64* tz = cz; cz = nz; nz = tz;
  }

  // final sim + argmax + k
  ga_bit<1><<<dim3(512), dim3(256), 0, stream>>>(cs, cz, inb, cbbT, nullptr, simI);
  k_argmax<<<dim3(1024), dim3(256), 0, stream>>>(simI, chg, out);
}

// Round 3
// 565.101 us; speedup vs baseline: 1.3745x; 1.0477x over previous
//
#include <hip/hip_runtime.h>

#define B_SZ 256
#define F_SZ 4
#define M_SZ 256
#define D_SZ 8192
#define NITER 10

typedef signed char i8;
typedef unsigned long long u64;
typedef signed char c16 __attribute__((ext_vector_type(16)));
typedef int v4i __attribute__((ext_vector_type(4)));

#define NBFM (B_SZ * F_SZ * M_SZ)   // 262144

// ---- workspace layout (bytes) ----
#define OFF_CB    ((size_t)0)          // i8  [F][M][D]      8 MB
#define OFF_CBT   ((size_t)8  << 20)   // i8  [F][D][M]      8 MB
#define OFF_IN8   ((size_t)16 << 20)   // i8  [B][D]         2 MB
#define OFF_CBBT  ((size_t)18 << 20)   // u64 [F][128][M]    1 MB
#define OFF_INB   ((size_t)19 << 20)   // u64 [B][128]       256 KB
#define OFF_ESB   ((size_t)20 << 20)   // u64 [B][F][128]    1 MB  (sign bits, in-place)
#define OFF_EZB   ((size_t)21 << 20)   // u64 [B][F][128]    1 MB  (zero bits, in-place)
#define OFF_SIMX  ((size_t)22 << 20)   // i8  [B*F][768]     768 KB (digit planes)
#define OFF_P1    ((size_t)23 << 20)   // i32 [24][B*F*M]    24 MB  (iter1 partials)
#define OFF_S32   ((size_t)48 << 20)   // i32 [F][D]         128 KB
#define OFF_PDIG  (OFF_S32 + (size_t)F_SZ * D_SZ * 4)   // i8 [3][F][D] 96 KB
#define OFF_CHG   (OFF_PDIG + (size_t)3 * F_SZ * D_SZ)  // int[16]

// ---------------- converts / init ----------------

__global__ __launch_bounds__(256) void k_cvt_cb(const float* __restrict__ src,
                                                i8* __restrict__ cb, i8* __restrict__ cbt) {
  __shared__ i8 tile[32][33];
  const int bid = blockIdx.x;           // 8192 = 4f * 8mt * 256dt
  const int f = bid >> 11;
  const int rem = bid & 2047;
  const int m0 = (rem >> 8) << 5;
  const int d0 = (rem & 255) << 5;
  const int t = threadIdx.x;
  const int i = t >> 3, j = (t & 7) << 2;
  const float4 v = *(const float4*)(src + ((size_t)(f * M_SZ + m0 + i)) * D_SZ + d0 + j);
  char4 c;
  c.x = v.x > 0.f ? 1 : -1;
  c.y = v.y > 0.f ? 1 : -1;
  c.z = v.z > 0.f ? 1 : -1;
  c.w = v.w > 0.f ? 1 : -1;
  *(char4*)(cb + ((size_t)(f * M_SZ + m0 + i)) * D_SZ + d0 + j) = c;
  tile[i][j + 0] = c.x; tile[i][j + 1] = c.y; tile[i][j + 2] = c.z; tile[i][j + 3] = c.w;
  __syncthreads();
  const int dd = t >> 3, jm = (t & 7) << 2;
  char4 o;
  o.x = tile[jm + 0][dd]; o.y = tile[jm + 1][dd]; o.z = tile[jm + 2][dd]; o.w = tile[jm + 3][dd];
  *(char4*)(cbt + ((size_t)(f * D_SZ + d0 + dd)) * M_SZ + m0 + jm) = o;
}

__global__ __launch_bounds__(256) void k_cvt_in(const float* __restrict__ src, i8* __restrict__ dst) {
  const int idx = blockIdx.x * 256 + threadIdx.x;   // 524288 float4s
  const float4 v = ((const float4*)src)[idx];
  char4 c;
  c.x = v.x > 0.f ? 1 : -1;
  c.y = v.y > 0.f ? 1 : -1;
  c.z = v.z > 0.f ? 1 : -1;
  c.w = v.w > 0.f ? 1 : -1;
  ((char4*)dst)[idx] = c;
}

__global__ __launch_bounds__(256) void k_pack_cb(const i8* __restrict__ cb, u64* __restrict__ cbbT) {
  const int id = blockIdx.x * 256 + threadIdx.x;   // 131072 = f*32768 + w*256 + m
  const int f = id >> 15;
  const int rem = id & 32767;
  const int w = rem >> 8;
  const int m = rem & 255;
  const i8* src = cb + ((size_t)(f * M_SZ + m)) * D_SZ + w * 64;
  u64 r = 0;
  #pragma unroll
  for (int k = 0; k < 4; ++k) {
    c16 v = *(const c16*)(src + k * 16);
    u64 part = 0;
    #pragma unroll
    for (int j = 0; j < 16; ++j) part |= ((u64)(((unsigned char)v[j]) >> 7)) << j;
    r |= part << (k * 16);
  }
  cbbT[((size_t)(f * 128 + w)) * 256 + m] = r;
}

__global__ __launch_bounds__(256) void k_pack_in(const i8* __restrict__ in8, u64* __restrict__ inb) {
  const int id = blockIdx.x * 256 + threadIdx.x;   // 32768 = b*128 + w
  const int b = id >> 7;
  const int w = id & 127;
  const i8* src = in8 + (size_t)b * D_SZ + w * 64;
  u64 r = 0;
  #pragma unroll
  for (int k = 0; k < 4; ++k) {
    c16 v = *(const c16*)(src + k * 16);
    u64 part = 0;
    #pragma unroll
    for (int j = 0; j < 16; ++j) part |= ((u64)(((unsigned char)v[j]) >> 7)) << j;
    r |= part << (k * 16);
  }
  inb[(size_t)b * 128 + w] = r;
}

__global__ __launch_bounds__(256) void k_S(const i8* __restrict__ cb, int* __restrict__ S) {
  const int id = blockIdx.x * 256 + threadIdx.x;    // 32768 = [f][d]
  const int f = id >> 13, d = id & 8191;
  const i8* p = cb + (size_t)f * M_SZ * D_SZ + d;
  int s = 0;
  for (int m = 0; m < M_SZ; ++m) s += p[(size_t)m * D_SZ];
  S[id] = s;
}

// P' = P/8 (exact: each S is even), 3 radix-255 signed digits in [-127,127]
__global__ __launch_bounds__(256) void k_P(const int* __restrict__ S, i8* __restrict__ pdig) {
  const int d = blockIdx.x * 256 + threadIdx.x;     // 8192
  const int s0 = S[d], s1 = S[D_SZ + d], s2 = S[2 * D_SZ + d], s3 = S[3 * D_SZ + d];
  int P[4];
  P[0] = s1 * s2 * s3;
  P[1] = s0 * s2 * s3;
  P[2] = s0 * s1 * s3;
  P[3] = s0 * s1 * s2;
  for (int f = 0; f < 4; ++f) {
    int x = P[f] >> 3;                 // exact (divisible by 8)
    #pragma unroll
    for (int p = 0; p < 2; ++p) {
      const int y = x + 127;
      const int q = (y >= 0) ? (y / 255) : -((-y + 254) / 255);   // floor(y/255)
      const int dg = x - q * 255;      // in [-127,127]
      pdig[((size_t)(p * F_SZ + f)) * D_SZ + d] = (i8)dg;
      x = q;
    }
    pdig[((size_t)(2 * F_SZ + f)) * D_SZ + d] = (i8)x;   // |x| <= ~34
  }
}

// ---------------- iteration-1 stage A (MFMA, 3 digit planes of P/8) ----------------
// grid 768: bid = s(8) + 8*( p(3) + 3*( f(4) + 4*ct(8) ) )

__global__ __launch_bounds__(256) void ga2_kernel(
    const i8* __restrict__ in8, const i8* __restrict__ cb,
    const i8* __restrict__ pdig, int* __restrict__ p1)
{
  __shared__ __align__(16) i8 lA[64 * 48];
  __shared__ __align__(16) i8 lB[128 * 48];

  const int bid = blockIdx.x;
  const int s = bid & 7;
  const int r = bid >> 3;
  const int p = r % 3;
  const int q = r / 3;
  const int f = q & 3;
  const int ct = q >> 2;
  const int b0 = (ct >> 1) * 64;
  const int m0 = (ct & 1) * 128;
  const int ksteps = 32;
  const int kbase = s << 10;

  const int t = threadIdx.x;
  const int lane = t & 63;
  const int wv = t >> 6;
  const int wrow = (wv >> 1) * 32;
  const int wcol = (wv & 1) * 64;

  const int arow = t >> 1;
  const int aoff = (t & 1) * 16;
  const i8* pB  = cb   + ((size_t)(f * M_SZ + m0 + arow)) * D_SZ + aoff;
  const i8* pDg = pdig + ((size_t)(p * F_SZ + f)) * D_SZ + aoff;
  const i8* pIn = in8  + (size_t)(b0 + arow) * D_SZ + aoff;

  v4i acc[2][4];
  #pragma unroll
  for (int tr = 0; tr < 2; ++tr)
    #pragma unroll
    for (int tc = 0; tc < 4; ++tc) acc[tr][tc] = 0;

  c16 va = 0, vb = 0;
  {
    const int kk = kbase;
    vb = (*(const c16*)(pB + kk)) * (*(const c16*)(pDg + kk));
    if (t < 128) va = *(const c16*)(pIn + kk);
  }

  for (int j = 0; j < ksteps; ++j) {
    c16 sa = va, sb = vb;
    if (j + 1 < ksteps) {
      const int kk = kbase + (j + 1) * 32;
      vb = (*(const c16*)(pB + kk)) * (*(const c16*)(pDg + kk));
      if (t < 128) va = *(const c16*)(pIn + kk);
    }
    __syncthreads();
    if (t < 128) *(c16*)&lA[arow * 48 + aoff] = sa;
    *(c16*)&lB[arow * 48 + aoff] = sb;
    __syncthreads();

    const int rsel = lane & 15;
    const int kq = (lane >> 4) * 8;
    long af[2], bf[4];
    #pragma unroll
    for (int tr = 0; tr < 2; ++tr) af[tr] = *(const long*)&lA[(wrow + tr * 16 + rsel) * 48 + kq];
    #pragma unroll
    for (int tc = 0; tc < 4; ++tc) bf[tc] = *(const long*)&lB[(wcol + tc * 16 + rsel) * 48 + kq];
    #pragma unroll
    for (int tr = 0; tr < 2; ++tr)
      #pragma unroll
      for (int tc = 0; tc < 4; ++tc)
        acc[tr][tc] = __builtin_amdgcn_mfma_i32_16x16x32_i8(af[tr], bf[tc], acc[tr][tc], 0, 0, 0);
  }

  const int colb = lane & 15;
  const int rowq = (lane >> 4) * 4;
  const size_t obase = (size_t)(p * 8 + s) * NBFM;
  #pragma unroll
  for (int tr = 0; tr < 2; ++tr)
    #pragma unroll
    for (int tc = 0; tc < 4; ++tc)
      #pragma unroll
      for (int rr = 0; rr < 4; ++rr) {
        const int b = b0 + wrow + tr * 16 + rowq + rr;
        const int m = m0 + wcol + tc * 16 + colb;
        p1[obase + (((size_t)(b * F_SZ + f)) << 8) + m] = acc[tr][tc][rr];
      }
}

// recombine 24 slices (3 planes x 8 splits, base 255) -> 3 radix-256 simx digits
__global__ __launch_bounds__(256) void k_digits1(const int* __restrict__ p1, i8* __restrict__ simx) {
  const int idx = blockIdx.x * 256 + threadIdx.x;
  long long g[3];
  #pragma unroll
  for (int p = 0; p < 3; ++p) {
    long long gg = 0;
    #pragma unroll
    for (int s = 0; s < 8; ++s) gg += (long long)p1[(size_t)(p * 8 + s) * NBFM + idx];
    g[p] = gg;
  }
  const long long sim = g[0] + 255LL * g[1] + 65025LL * g[2];
  int x = (int)sim;
  const int r1 = (x + 128) >> 8;
  const int d0 = x - (r1 << 8);
  const int r2 = (r1 + 128) >> 8;
  const int d1 = r1 - (r2 << 8);
  const size_t bf = (size_t)(idx >> 8);
  const int m = idx & 255;
  simx[bf * 768 + m] = (i8)d0;
  simx[bf * 768 + 256 + m] = (i8)d1;
  simx[bf * 768 + 512 + m] = (i8)r2;
}

// ---------------- bitwise stage A (iters >= 2) ----------------
// A = in ^ es(f0)^es(f1)^es(f2), nz = ~(ez|ez|ez) -> simx 2 digit planes
// grid 512 = f(4) x btile(128, 2 rows each); 256 threads = 256 m

__global__ __launch_bounds__(256) void ga_bit(
    const u64* __restrict__ esb, const u64* __restrict__ ezb,
    const u64* __restrict__ inb, const u64* __restrict__ cbbT,
    i8* __restrict__ simx, const int* __restrict__ changed, int it)
{
  __shared__ u64 AL[128][4];    // [w][{s0,nz0,s1,nz1}]
  __shared__ int C0[2];

  if (changed[it - 1] == 0) return;   // converged earlier -> no-op iteration

  const int bid = blockIdx.x;
  const int f = bid & 3;
  const int b0 = (bid >> 2) * 2;
  const int t = threadIdx.x;
  if (t < 2) C0[t] = 0;
  __syncthreads();

  {
    const int r = t >> 7, w = t & 127;
    const int b = b0 + r;
    int ffs[3]; int c = 0;
    for (int ff = 0; ff < 4; ++ff) if (ff != f) ffs[c++] = ff;
    const size_t base = (size_t)b * 4 * 128;
    const u64 s = inb[(size_t)b * 128 + w]
      ^ esb[base + ffs[0] * 128 + w] ^ esb[base + ffs[1] * 128 + w] ^ esb[base + ffs[2] * 128 + w];
    const u64 nz = ~(ezb[base + ffs[0] * 128 + w] | ezb[base + ffs[1] * 128 + w] | ezb[base + ffs[2] * 128 + w]);
    AL[w][r * 2] = s;
    AL[w][r * 2 + 1] = nz;
    int pcv = (int)__popcll(nz);
    #pragma unroll
    for (int off = 32; off >= 1; off >>= 1) pcv += __shfl_down(pcv, off);
    if ((t & 63) == 0) atomicAdd(&C0[r], pcv);
  }
  __syncthreads();

  const int m = t;
  int a0 = 0, a1 = 0;
  const u64* pc = cbbT + (size_t)f * 128 * 256 + m;
  #pragma unroll 4
  for (int w = 0; w < 128; ++w) {
    const u64 cbw = pc[w * 256];
    const u64 s0 = AL[w][0], z0 = AL[w][1], s1 = AL[w][2], z1 = AL[w][3];
    a0 += (int)__popcll((s0 ^ cbw) & z0);
    a1 += (int)__popcll((s1 ^ cbw) & z1);
  }
  const int sim0 = C0[0] - 2 * a0;
  const int sim1 = C0[1] - 2 * a1;

  int d1 = (sim0 + 128) >> 8; int d0v = sim0 - (d1 << 8);
  const size_t bf0 = ((size_t)b0 * 4 + f) * 768;
  simx[bf0 + m] = (i8)d0v; simx[bf0 + 256 + m] = (i8)d1;
  d1 = (sim1 + 128) >> 8; d0v = sim1 - (d1 << 8);
  const size_t bf1 = ((size_t)(b0 + 1) * 4 + f) * 768;
  simx[bf1 + m] = (i8)d0v; simx[bf1 + 256 + m] = (i8)d1;
}

// ---------------- stage B GEMM (out -> sign -> packed est bits, in-place) ----------------
// grid 1024 = f(4) x ct(256: 4 btiles x 64 dtiles). B staged once in frag-linear LDS.

template<int NP, bool FIRST>
__global__ __launch_bounds__(256) void gb_kernel(
    const i8* __restrict__ simx, const i8* __restrict__ cbt,
    u64* __restrict__ esb, u64* __restrict__ ezb,
    const int* __restrict__ S32,
    int* __restrict__ changed, int it)
{
  __shared__ __align__(16) i8 lB[8 * 8 * 64 * 8];   // 32 KB: [ks][tile][lane][8]
  __shared__ int chgf;

  if (!FIRST) { if (changed[it - 1] == 0) return; }

  const int bid = blockIdx.x;
  const int f = bid & 3;
  const int ct = bid >> 2;
  const int b0 = (ct >> 6) * 64;
  const int d0 = (ct & 63) * 128;

  const int t = threadIdx.x;
  if (t == 0) chgf = 0;
  const int lane = t & 63;
  const int wv = t >> 6;
  const int wrow = (wv >> 1) * 32;
  const int wcol = (wv & 1) * 64;

  // ---- stage B tile into frag-linear LDS ----
  {
    const int c = t & 15;          // 16-byte chunk of m
    const int dr0 = t >> 4;        // base d row
    const int ks = c >> 1;
    const int q0 = (c & 1) * 2;
    #pragma unroll
    for (int i = 0; i < 8; ++i) {
      const int dr = dr0 + i * 16;
      union { c16 v; u64 u[2]; } x;
      x.v = *(const c16*)(cbt + ((size_t)(f * D_SZ + d0 + dr)) * M_SZ + c * 16);
      const int tile = dr >> 4;
      const int col = dr & 15;
      *(u64*)&lB[((((ks * 8 + tile) * 4 + q0) * 16 + col)) * 8] = x.u[0];
      *(u64*)&lB[((((ks * 8 + tile) * 4 + q0 + 1) * 16 + col)) * 8] = x.u[1];
    }
  }
  __syncthreads();

  v4i acc[NP][2][4];
  #pragma unroll
  for (int pp = 0; pp < NP; ++pp)
    #pragma unroll
    for (int tr = 0; tr < 2; ++tr)
      #pragma unroll
      for (int tc = 0; tc < 4; ++tc) acc[pp][tr][tc] = 0;

  const int rsel = lane & 15;
  const int kq = (lane >> 4) * 8;
  const int tb = wcol >> 4;

  #pragma unroll
  for (int ks = 0; ks < 8; ++ks) {
    long bf[4];
    #pragma unroll
    for (int tc = 0; tc < 4; ++tc)
      bf[tc] = *(const long*)&lB[((ks * 8 + tb + tc) * 64 + lane) * 8];
    #pragma unroll
    for (int pp = 0; pp < NP; ++pp) {
      long af[2];
      #pragma unroll
      for (int tr = 0; tr < 2; ++tr) {
        const int row = b0 + wrow + tr * 16 + rsel;
        af[tr] = *(const long*)(simx + ((size_t)(row * 4 + f)) * 768 + pp * 256 + ks * 32 + kq);
      }
      #pragma unroll
      for (int tr = 0; tr < 2; ++tr)
        #pragma unroll
        for (int tc = 0; tc < 4; ++tc)
          acc[pp][tr][tc] = __builtin_amdgcn_mfma_i32_16x16x32_i8(af[tr], bf[tc], acc[pp][tr][tc], 0, 0, 0);
    }
  }

  // ---- epilogue: sign, ballot-pack, change-detect, in-place store ----
  bool chl = false;
  const int colb = lane & 15;

  #pragma unroll
  for (int tr = 0; tr < 2; ++tr) {
    unsigned long long bs[4][4], bz[4][4];   // [r][tc]
    #pragma unroll
    for (int rr = 0; rr < 4; ++rr)
      #pragma unroll
      for (int tc = 0; tc < 4; ++tc) {
        int o = acc[0][tr][tc][rr];
        if (NP > 1) o += acc[1][tr][tc][rr] * 256;
        if (NP > 2) o += acc[2][tr][tc][rr] * 65536;
        bs[rr][tc] = __ballot(o < 0);
        bz[rr][tc] = __ballot(o == 0);
        if (FIRST) {
          const int sg = (o > 0) - (o < 0);
          const int d = d0 + wcol + tc * 16 + colb;
          chl |= (sg != S32[f * D_SZ + d]);
        }
      }
    u64 ws = 0, wz = 0;
    #pragma unroll
    for (int rl = 0; rl < 16; ++rl) {
      const int g = rl >> 2, rr = rl & 3;
      u64 vs = 0, vz = 0;
      #pragma unroll
      for (int tc = 0; tc < 4; ++tc) {
        vs |= ((bs[rr][tc] >> (g * 16)) & 0xFFFFull) << (tc * 16);
        vz |= ((bz[rr][tc] >> (g * 16)) & 0xFFFFull) << (tc * 16);
      }
      if (lane == rl) { ws = vs; wz = vz; }
    }
    if (lane < 16) {
      const int row = b0 + wrow + tr * 16 + lane;
      const size_t wi = ((size_t)(row * 4 + f)) * 128 + ((d0 + wcol) >> 6);
      if (!FIRST) chl |= (ws != esb[wi]) | (wz != ezb[wi]);
      esb[wi] = ws;
      ezb[wi] = wz;
    }
  }
  if (chl) atomicOr(&chgf, 1);
  __syncthreads();
  if (t == 0 && chgf) atomicOr(&changed[it], 1);
}

// ---------------- final: sim + argmax + k (fused) ----------------
// grid 512 = f(4) x btile(128, 2 rows each)

__global__ __launch_bounds__(256) void k_final(
    const u64* __restrict__ esb, const u64* __restrict__ ezb,
    const u64* __restrict__ cbbT, const int* __restrict__ chg,
    int* __restrict__ out)
{
  __shared__ u64 AL[128][4];
  __shared__ int C0[2];
  __shared__ long long red0[256], red1[256];

  const int bid = blockIdx.x;
  const int f = bid & 3;
  const int b0 = (bid >> 2) * 2;
  const int t = threadIdx.x;
  if (t < 2) C0[t] = 0;
  __syncthreads();

  {
    const int r = t >> 7, w = t & 127;
    const int b = b0 + r;
    const size_t a = ((size_t)b * 4 + f) * 128 + w;
    const u64 s = esb[a];
    const u64 nz = ~ezb[a];
    AL[w][r * 2] = s;
    AL[w][r * 2 + 1] = nz;
    int pcv = (int)__popcll(nz);
    #pragma unroll
    for (int off = 32; off >= 1; off >>= 1) pcv += __shfl_down(pcv, off);
    if ((t & 63) == 0) atomicAdd(&C0[r], pcv);
  }
  __syncthreads();

  const int m = t;
  int a0 = 0, a1 = 0;
  const u64* pc = cbbT + (size_t)f * 128 * 256 + m;
  #pragma unroll 4
  for (int w = 0; w < 128; ++w) {
    const u64 cbw = pc[w * 256];
    const u64 s0 = AL[w][0], z0 = AL[w][1], s1 = AL[w][2], z1 = AL[w][3];
    a0 += (int)__popcll((s0 ^ cbw) & z0);
    a1 += (int)__popcll((s1 ^ cbw) & z1);
  }
  const int sim0 = C0[0] - 2 * a0;
  const int sim1 = C0[1] - 2 * a1;

  red0[m] = ((long long)sim0 << 32) | (long long)(unsigned)(255 - m);
  red1[m] = ((long long)sim1 << 32) | (long long)(unsigned)(255 - m);
  __syncthreads();
  for (int s2 = 128; s2 > 0; s2 >>= 1) {
    if (m < s2) {
      if (red0[m + s2] > red0[m]) red0[m] = red0[m + s2];
      if (red1[m + s2] > red1[m]) red1[m] = red1[m + s2];
    }
    __syncthreads();
  }
  if (m == 0) {
    out[b0 * 4 + f] = 255 - (int)(red0[0] & 0xFFFF);
    out[(b0 + 1) * 4 + f] = 255 - (int)(red1[0] & 0xFFFF);
    if (bid == 0) {
      int k = NITER;
      for (int i = 1; i <= NITER; ++i) if (chg[i] == 0) { k = i; break; }
      out[B_SZ * F_SZ] = k;
    }
  }
}

// ---------------- host ----------------

extern "C" void kernel_launch(void* const* d_in, const int* in_sizes, int n_in,
                              void* d_out, int out_size, void* d_ws, size_t ws_size,
                              hipStream_t stream) {
  const float* f_in = (const float*)d_in[0];   // [B][D]
  const float* f_cb = (const float*)d_in[1];   // [F][M][D]
  int* out = (int*)d_out;
  char* ws = (char*)d_ws;

  i8*  cb8  = (i8*)(ws + OFF_CB);
  i8*  cbt8 = (i8*)(ws + OFF_CBT);
  i8*  in8  = (i8*)(ws + OFF_IN8);
  u64* cbbT = (u64*)(ws + OFF_CBBT);
  u64* inb  = (u64*)(ws + OFF_INB);
  u64* esb  = (u64*)(ws + OFF_ESB);
  u64* ezb  = (u64*)(ws + OFF_EZB);
  i8*  simx = (i8*)(ws + OFF_SIMX);
  int* p1   = (int*)(ws + OFF_P1);
  int* S32  = (int*)(ws + OFF_S32);
  i8*  pdig = (i8*)(ws + OFF_PDIG);
  int* chg  = (int*)(ws + OFF_CHG);

  hipMemsetAsync(chg, 0, 64, stream);
  k_cvt_cb<<<dim3(8192), dim3(256), 0, stream>>>(f_cb, cb8, cbt8);
  k_cvt_in<<<dim3(2048), dim3(256), 0, stream>>>(f_in, in8);
  k_pack_cb<<<dim3(512), dim3(256), 0, stream>>>(cb8, cbbT);
  k_pack_in<<<dim3(128), dim3(256), 0, stream>>>(in8, inb);
  k_S<<<dim3(128), dim3(256), 0, stream>>>(cb8, S32);
  k_P<<<dim3(32), dim3(256), 0, stream>>>(S32, pdig);

  // iteration 1 (big-integer est0 via P/8 digit planes, MFMA)
  ga2_kernel<<<dim3(768), dim3(256), 0, stream>>>(in8, cb8, pdig, p1);
  k_digits1<<<dim3(1024), dim3(256), 0, stream>>>(p1, simx);
  gb_kernel<3, true><<<dim3(1024), dim3(256), 0, stream>>>(
      simx, cbt8, esb, ezb, S32, chg, 1);

  for (int it = 2; it <= NITER; ++it) {
    ga_bit<<<dim3(512), dim3(256), 0, stream>>>(esb, ezb, inb, cbbT, simx, chg, it);
    gb_kernel<2, false><<<dim3(1024), dim3(256), 0, stream>>>(
        simx, cbt8, esb, ezb, nullptr, chg, it);
  }

  // final sim + argmax + k (always runs; esb/ezb hold the converged state)
  k_final<<<dim3(512), dim3(256), 0, stream>>>(esb, ezb, cbbT, chg, out);
}